// Round 13
// baseline (146.375 us; speedup 1.0000x reference)
//
#include <hip/hip_runtime.h>
#include <hip/hip_bf16.h>

typedef __attribute__((ext_vector_type(8))) short short8;
typedef __attribute__((ext_vector_type(8))) __bf16 bf16x8;
typedef __attribute__((ext_vector_type(4))) float f32x4;

#define MFMA(a, b, c) __builtin_amdgcn_mfma_f32_16x16x32_bf16((a), (b), (c), 0, 0, 0)
#define SCALE 0.0625f

static __device__ __forceinline__ void gload16(const void* g, void* l) {
  __builtin_amdgcn_global_load_lds(
      (const __attribute__((address_space(1))) void*)g,
      (__attribute__((address_space(3))) void*)l, 16, 0, 0);
}

static __device__ __forceinline__ unsigned short f2b(float f) {
  union { __hip_bfloat16 h; unsigned short u; } cv;
  cv.h = __float2bfloat16(f);
  return cv.u;
}

// ---- fused prep: convert_x + pack_bias + transpose_w(Wq,Wk,Wv) -------------
__global__ __launch_bounds__(256) void prep_kern(
    const float* __restrict__ x, unsigned short* __restrict__ xb,
    const float* __restrict__ bq, const float* __restrict__ bk,
    const float* __restrict__ bv, float* __restrict__ bc,
    const float* __restrict__ Wq, const float* __restrict__ Wk,
    const float* __restrict__ Wv, unsigned short* __restrict__ wt) {
  __shared__ __align__(16) unsigned short tile[64][72];
  int bid = blockIdx.x, t = threadIdx.x;
  if (bid < 4096) {
    long i = ((long)bid * 256 + t) * 8;
    float4 a = *reinterpret_cast<const float4*>(x + i);
    float4 b = *reinterpret_cast<const float4*>(x + i + 4);
    short8 o;
    o[0] = (short)f2b(a.x); o[1] = (short)f2b(a.y); o[2] = (short)f2b(a.z); o[3] = (short)f2b(a.w);
    o[4] = (short)f2b(b.x); o[5] = (short)f2b(b.y); o[6] = (short)f2b(b.z); o[7] = (short)f2b(b.w);
    *reinterpret_cast<short8*>(xb + i) = o;
    return;
  }
  if (bid < 4102) {
    int i = (bid - 4096) * 256 + t;
    float v = (i < 256) ? bq[i] : (i < 512) ? bk[i - 256] : bv[i - 512];
    bc[i] = v;
    return;
  }
  const float* src; unsigned short* dst; int ldsrc, lam;
  if (bid < 4166)      { lam = bid - 4102; src = Wq; dst = wt;              ldsrc = 256;
                         lam = (lam & 3) | ((lam >> 2) << 8); }
  else if (bid < 4230) { lam = bid - 4166; src = Wk; dst = wt + 256 * 1024; ldsrc = 256;
                         lam = (lam & 3) | ((lam >> 2) << 8); }
  else                 { lam = bid - 4230; src = Wv; dst = wt + 512 * 1024; ldsrc = 1024;
                         lam = (lam & 15) | ((lam >> 4) << 8); }
  int c0 = (lam & 255) * 64, r0 = (lam >> 8) * 64;
  #pragma unroll
  for (int it = 0; it < 4; ++it) {
    int idx = it * 1024 + t * 4;
    int row = idx >> 6, col = idx & 63;
    float4 v = *reinterpret_cast<const float4*>(src + (long)(r0 + row) * ldsrc + c0 + col);
    tile[row][col + 0] = f2b(v.x); tile[row][col + 1] = f2b(v.y);
    tile[row][col + 2] = f2b(v.z); tile[row][col + 3] = f2b(v.w);
  }
  __syncthreads();
  #pragma unroll
  for (int it = 0; it < 4; ++it) {
    int idx = it * 1024 + t * 4;
    int orow = idx >> 6, ocol = idx & 63;
    ushort4 o;
    o.x = tile[ocol + 0][orow]; o.y = tile[ocol + 1][orow];
    o.z = tile[ocol + 2][orow]; o.w = tile[ocol + 3][orow];
    *reinterpret_cast<ushort4*>(dst + (long)(c0 + orow) * 1024 + r0 + ocol) = o;
  }
}

// ============================================================================
// gemm_pi (QKV + score): r11/r12-proven, unchanged.
// ============================================================================
template <int SWZ, int BN, bool BIAS, bool VSPLIT, bool EXPSUM>
__global__ __launch_bounds__(512, 2) void gemm_pi(
    const unsigned short* __restrict__ A, const unsigned short* __restrict__ B,
    const float* __restrict__ bias, void* __restrict__ Cout,
    int NT, int lda, int ldb, int ldc,
    long batchA, long batchB, long batchC,
    float* __restrict__ lpart,
    unsigned short* __restrict__ vT) {
  constexpr int WM = 128;
  constexpr int WN = BN / 4;
  constexpr int NF = BN / 64;
  constexpr int BR = BN / 64;
  constexpr int ASH = 256 * 64;
  constexpr int TSH = ASH + BN * 64;
  __shared__ __align__(128) unsigned short lds[2 * TSH];

  int bid = blockIdx.x;
  int b = 0, tm, tn;
  if constexpr (SWZ == 0) {
    int xcd = bid & 7, s = bid >> 3;
    tm = xcd * 4 + (s >> 3); tn = s & 7;
  } else {
    int xcd = bid & 7, s = bid >> 3;
    b = xcd >> 1; tm = (xcd & 1) * 4 + (s >> 3); tn = s & 7;
  }

  int t = threadIdx.x, w = t >> 6, l = t & 63;
  int wr = w >> 2, wc = w & 3;
  int g = l >> 4, c = l & 15;

  f32x4 acc[8][NF];
  #pragma unroll
  for (int m = 0; m < 8; ++m)
    #pragma unroll
    for (int n = 0; n < NF; ++n) acc[m][n] = (f32x4){0.f, 0.f, 0.f, 0.f};

  int srow = t >> 3;
  int scb = (t & 7) * 16;
  const unsigned short* aptr = A + (long)b * batchA + (long)(tm * 256) * lda;
  const unsigned short* bptr = B + (long)b * batchB + (long)(tn * BN) * ldb;
  int kb = scb ^ ((srow & 7) << 4);

  auto stageA = [&](int buf, int k0, int r) {
    int row = r * 64 + srow;
    gload16(aptr + (long)row * lda + k0 + (kb >> 1),
            lds + buf * TSH + r * 4096 + t * 8);
  };
  auto stageB = [&](int buf, int k0, int r) {
    int row = r * 64 + srow;
    gload16(bptr + (long)row * ldb + k0 + (kb >> 1),
            lds + buf * TSH + ASH + r * 4096 + t * 8);
  };
  auto ldA = [&](const char* abase, int mh, int kh, int m) {
    int row = wr * WM + mh * 64 + m * 16 + c;
    int pb = row * 128 + (kh * 32 + g * 8) * 2;
    pb ^= ((pb >> 7) & 7) << 4;
    return *reinterpret_cast<const bf16x8*>(abase + pb);
  };
  auto ldB = [&](const char* bbase, int kh, int n) {
    int row = wc * WN + n * 16 + c;
    int pb = row * 128 + (kh * 32 + g * 8) * 2;
    pb ^= ((pb >> 7) & 7) << 4;
    return *reinterpret_cast<const bf16x8*>(bbase + pb);
  };

  #pragma unroll
  for (int r = 0; r < BR; ++r) stageB(0, 0, r);
  stageA(0, 0, 0); stageA(0, 0, 2); stageA(0, 0, 1); stageA(0, 0, 3);
  asm volatile("s_waitcnt vmcnt(0)" ::: "memory");
  __builtin_amdgcn_s_barrier();

  for (int kt = 0; kt < NT; ++kt) {
    int cur = kt & 1, nb = cur ^ 1;
    const char* abase = (const char*)(lds + cur * TSH);
    const char* bbase = (const char*)(lds + cur * TSH + ASH);
    bool more = (kt + 1) < NT;
    int k1 = (kt + 1) * 64;
    bf16x8 bfr[NF];
    #pragma unroll
    for (int p = 0; p < 4; ++p) {
      const int kh = p >> 1, mh = p & 1;
      bf16x8 af[4];
      #pragma unroll
      for (int m = 0; m < 4; ++m) af[m] = ldA(abase, mh, kh, m);
      if (mh == 0) {
        #pragma unroll
        for (int n = 0; n < NF; ++n) bfr[n] = ldB(bbase, kh, n);
      }
      if (more) {
        if constexpr (BN == 256) {
          if      (p == 0) { stageB(nb, k1, 0); stageB(nb, k1, 1); }
          else if (p == 1) { stageB(nb, k1, 2); stageB(nb, k1, 3); }
          else if (p == 2) { stageA(nb, k1, 0); stageA(nb, k1, 2); }
          else             { stageA(nb, k1, 1); stageA(nb, k1, 3); }
        } else {
          if      (p == 0) { stageB(nb, k1, 0); stageB(nb, k1, 1); stageB(nb, k1, 2); }
          else if (p == 1) { stageA(nb, k1, 0); stageA(nb, k1, 2); }
          else if (p == 2) { stageA(nb, k1, 1); stageA(nb, k1, 3); }
        }
      }
      __builtin_amdgcn_s_barrier();
      asm volatile("s_waitcnt lgkmcnt(0)" ::: "memory");
      __builtin_amdgcn_sched_barrier(0);
      __builtin_amdgcn_s_setprio(1);
      #pragma unroll
      for (int m = 0; m < 4; ++m)
        #pragma unroll
        for (int n = 0; n < NF; ++n)
          acc[mh * 4 + m][n] = MFMA(af[m], bfr[n], acc[mh * 4 + m][n]);
      __builtin_amdgcn_s_setprio(0);
      if (p == 0) {
        if (kt == NT - 1) asm volatile("s_waitcnt vmcnt(0)" ::: "memory");
        else if (BN == 256) asm volatile("s_waitcnt vmcnt(2)" ::: "memory");
        else                asm volatile("s_waitcnt vmcnt(3)" ::: "memory");
      }
      if (p == 3 && more) {
        asm volatile("s_waitcnt vmcnt(2)" ::: "memory");
      }
      __builtin_amdgcn_s_barrier();
    }
  }

  int rbase = tm * 256 + wr * WM + g * 4;
  int c0 = tn * BN + wc * WN + c;

  if constexpr (EXPSUM) {
    __shared__ float lred[4][256];
    #pragma unroll
    for (int mi = 0; mi < 8; ++mi) {
      int roff = (mi / 4) * 64 + (mi % 4) * 16;
      #pragma unroll
      for (int j = 0; j < 4; ++j) {
        long ob = (long)b * batchC + (long)(rbase + roff + j) * ldc + c0;
        float rs = 0.f;
        #pragma unroll
        for (int n = 0; n < NF; ++n) {
          float pv = __expf(acc[mi][n][j] * SCALE);
          ((unsigned short*)Cout)[ob + n * 16] = f2b(pv);
          rs += pv;
        }
        rs += __shfl_xor(rs, 1); rs += __shfl_xor(rs, 2);
        rs += __shfl_xor(rs, 4); rs += __shfl_xor(rs, 8);
        if (c == 0) lred[wc][wr * WM + roff + g * 4 + j] = rs;
      }
    }
    __syncthreads();
    for (int rr = t; rr < 256; rr += 512) {
      float s = lred[0][rr] + lred[1][rr] + lred[2][rr] + lred[3][rr];
      lpart[((long)b * 2048 + tm * 256 + rr) * 8 + tn] = s;
    }
  } else {
    #pragma unroll
    for (int mi = 0; mi < 8; ++mi) {
      int roff = (mi / 4) * 64 + (mi % 4) * 16;
      int s0 = (rbase + roff) & 2047;
      #pragma unroll
      for (int n = 0; n < NF; ++n) {
        int col = c0 + n * 16;
        float bv = BIAS ? bias[col] : 0.f;
        if (VSPLIT && (col - c) >= 512) {
          int bb = tm >> 3;
          ushort4 pk;
          pk.x = f2b(acc[mi][n][0] + bv); pk.y = f2b(acc[mi][n][1] + bv);
          pk.z = f2b(acc[mi][n][2] + bv); pk.w = f2b(acc[mi][n][3] + bv);
          *reinterpret_cast<ushort4*>(vT + (long)bb * 2097152 +
                                      (long)(col - 512) * 2048 + s0) = pk;
        } else {
          long rowb = (long)b * batchC + (long)(rbase + roff) * ldc + col;
          #pragma unroll
          for (int j = 0; j < 4; ++j)
            ((unsigned short*)Cout)[rowb + (long)j * ldc] = f2b(acc[mi][n][j] + bv);
        }
      }
    }
  }
}

// ============================================================================
// gemm_pv (PV): direct-global A-fragments (attn rows are wave-exclusive ->
// LDS staging of A was pure overhead: -33% ds_reads, -33% DMA). B (vT) stays
// LDS-staged (shared). 1024 thr = 16 waves (4M x 4N), wave 32x64, 3-buffer
// B-only LDS (96KB). A prefetch distance 1 tile via unroll-2 ping-pong reg
// sets (static names, rule #20). Explicit vmcnt(2) retires B-DMA(t+1)
// (order-robust: retires all-but-2-newest); compiler inserts precise waits
// for the A reg-loads and B ds_reads. linv folded into prologue.
// ============================================================================
__global__ __launch_bounds__(1024, 4) void gemm_pv(
    const unsigned short* __restrict__ A,   // attn [4][2048][2048] bf16
    const unsigned short* __restrict__ B,   // vT   [4][1024][2048] bf16
    float* __restrict__ Cout,               // out  [4][2048][1024] f32
    const float* __restrict__ lpart) {      // [4*2048][8] row partials
  constexpr int NT = 32;
  constexpr int BSH = 256 * 64;             // B tile shorts (32KB)
  __shared__ __align__(128) unsigned short lds[3 * BSH];
  __shared__ float linv_s[128];

  int bid = blockIdx.x;                     // 256 = 8 xcd * 32
  int xcd = bid & 7, sidx = bid >> 3;
  int b = xcd >> 1;
  int tm = (xcd & 1) * 8 + (sidx >> 2), tn = sidx & 3;

  int t = threadIdx.x, w = t >> 6, l = t & 63;
  int wr = w >> 2, wc = w & 3;              // 4 x 4 wave grid
  int g = l >> 4, c = l & 15;

  // fold linv: 1/sum of the 8 per-slice partials, rows tm*128..+127
  if (t < 128) {
    const float* lp = lpart + ((long)b * 2048 + tm * 128 + t) * 8;
    float s = lp[0] + lp[1] + lp[2] + lp[3] + lp[4] + lp[5] + lp[6] + lp[7];
    linv_s[t] = 1.f / s;
  }

  f32x4 acc[2][4];
  #pragma unroll
  for (int m = 0; m < 2; ++m)
    #pragma unroll
    for (int n = 0; n < 4; ++n) acc[m][n] = (f32x4){0.f, 0.f, 0.f, 0.f};

  int srow = t >> 3;                        // 0..127
  int scb = (t & 7) * 16;
  int kb = scb ^ ((srow & 7) << 4);
  const unsigned short* aptr = A + (long)b * 4194304 + (long)(tm * 128) * 2048;
  const unsigned short* bptr = B + (long)b * 2097152 + (long)(tn * 256) * 2048;

  auto stageB = [&](int buf, int kt2) {     // 2 DMA loads: 256 rows x 64 cols
    int k0 = kt2 * 64;
    #pragma unroll
    for (int r = 0; r < 2; ++r) {
      int row = r * 128 + srow;
      gload16(bptr + (long)row * 2048 + k0 + (kb >> 1),
              lds + buf * BSH + r * 8192 + t * 8);
    }
  };

  // per-lane A-fragment row pointers (rows wr*32 + {0,16} + c)
  const unsigned short* arow0 = aptr + (long)(wr * 32 + c) * 2048;
  const unsigned short* arow1 = aptr + (long)(wr * 32 + 16 + c) * 2048;
  auto LOADA = [&](bf16x8 (&af)[2][2], int kt2) {
    int k0 = kt2 * 64 + g * 8;
    af[0][0] = *reinterpret_cast<const bf16x8*>(arow0 + k0);
    af[0][1] = *reinterpret_cast<const bf16x8*>(arow1 + k0);
    af[1][0] = *reinterpret_cast<const bf16x8*>(arow0 + k0 + 32);
    af[1][1] = *reinterpret_cast<const bf16x8*>(arow1 + k0 + 32);
  };

  bf16x8 afA[2][2], afB[2][2];
  LOADA(afA, 0);
  stageB(0, 0); stageB(1, 1);
  asm volatile("s_waitcnt vmcnt(2)" ::: "memory");  // B(0) certainly retired
  __builtin_amdgcn_s_barrier();

#define PV_TILE(T, CUR, NXT)                                                 \
  {                                                                          \
    const char* bb = (const char*)(lds + ((T) % 3) * BSH);                   \
    if ((T) + 1 < NT) LOADA(NXT, (T) + 1);                                   \
    if ((T) + 2 < NT) stageB(((T) + 2) % 3, (T) + 2);                        \
    bf16x8 bf[2][4];                                                         \
    _Pragma("unroll")                                                        \
    for (int sk = 0; sk < 2; ++sk) {                                         \
      _Pragma("unroll")                                                      \
      for (int n = 0; n < 4; ++n) {                                          \
        int p = (wc * 64 + n * 16 + c) * 128 + (sk * 32 + g * 8) * 2;        \
        p ^= ((p >> 7) & 7) << 4;                                            \
        bf[sk][n] = *reinterpret_cast<const bf16x8*>(bb + p);                 \
      }                                                                      \
    }                                                                        \
    __builtin_amdgcn_s_setprio(1);                                           \
    _Pragma("unroll")                                                        \
    for (int sk = 0; sk < 2; ++sk) {                                         \
      _Pragma("unroll")                                                      \
      for (int m = 0; m < 2; ++m) {                                          \
        _Pragma("unroll")                                                    \
        for (int n = 0; n < 4; ++n)                                          \
          acc[m][n] = MFMA(CUR[sk][m], bf[sk][n], acc[m][n]);                \
      }                                                                      \
    }                                                                        \
    __builtin_amdgcn_s_setprio(0);                                           \
    if ((T) < NT - 1) {                                                      \
      asm volatile("s_waitcnt vmcnt(2)" ::: "memory");                       \
      __builtin_amdgcn_s_barrier();                                          \
    }                                                                        \
  }

  for (int kt = 0; kt < NT; kt += 2) {
    PV_TILE(kt, afA, afB)
    PV_TILE(kt + 1, afB, afA)
  }
#undef PV_TILE

  // epilogue: C/D layout col = lane&15, row = (lane>>4)*4 + j
  int rloc = wr * 32 + g * 4;
  int c0 = tn * 256 + wc * 64 + c;
  #pragma unroll
  for (int mi = 0; mi < 2; ++mi) {
    float lv[4];
    #pragma unroll
    for (int j = 0; j < 4; ++j)
      lv[j] = linv_s[rloc + mi * 16 + j];
    #pragma unroll
    for (int n = 0; n < 4; ++n) {
      long rowb = (long)b * 2097152 + (long)(tm * 128 + rloc + mi * 16) * 1024
                + c0 + n * 16;
      #pragma unroll
      for (int j = 0; j < 4; ++j)
        Cout[rowb + (long)j * 1024] = acc[mi][n][j] * lv[j];
    }
  }
}

extern "C" void kernel_launch(void* const* d_in, const int* in_sizes, int n_in,
                              void* d_out, int out_size, void* d_ws, size_t ws_size,
                              hipStream_t stream) {
  (void)in_sizes; (void)n_in; (void)out_size; (void)ws_size;
  const float* x  = (const float*)d_in[0];
  const float* Wq = (const float*)d_in[1];
  const float* bq = (const float*)d_in[2];
  const float* Wk = (const float*)d_in[3];
  const float* bk = (const float*)d_in[4];
  const float* Wv = (const float*)d_in[5];
  const float* bv = (const float*)d_in[6];
  float* out = (float*)d_out;
  char* ws = (char*)d_ws;

  unsigned short* xb   = (unsigned short*)(ws + 0);          // 16,777,216
  float*          lpart= (float*)         (ws + 0);          //    262,144 (overlay)
  unsigned short* wt   = (unsigned short*)(ws + 16777216);   //  3,145,728
  float*          bc   = (float*)         (ws + 19922944);   //      6,144
  unsigned short* qkv  = (unsigned short*)(ws + 19929088);   // 25,165,824
  unsigned short* vT   = (unsigned short*)(ws + 45094912);   // 16,777,216
  unsigned short* attn = (unsigned short*)(ws + 61872128);   // 33,554,432

  // fused prep (convert_x + pack_bias + Wq/Wk/Wv transpose)
  prep_kern<<<4486, 256, 0, stream>>>(x, xb, bq, bk, bv, bc, Wq, Wk, Wv, wt);

  // qkv = xb @ wt^T + bias; V columns stream directly to vT (BN=192, 256 blk)
  gemm_pi<0, 192, true, true, false><<<dim3(256), 512, 0, stream>>>(
      xb, wt, bc, qkv, 16, 1024, 1024, 1536, 0, 0, 0, nullptr, vT);

  // attn = exp(q.k/16) (unnormalized) + row partial sums
  gemm_pi<1, 256, false, false, true><<<dim3(256), 512, 0, stream>>>(
      qkv, qkv + 256, nullptr, attn, 4, 1536, 1536, 2048,
      (long)2048 * 1536, (long)2048 * 1536, (long)2048 * 2048, lpart, nullptr);

  // out = (attn @ vT^T) * linv  (direct-global A, linv folded in)
  gemm_pv<<<dim3(256), 1024, 0, stream>>>(attn, vT, out, lpart);
}

// Round 14
// 99.203 us; speedup vs baseline: 1.4755x; 1.4755x over previous
//
#include <hip/hip_runtime.h>
#include <hip/hip_bf16.h>

typedef __attribute__((ext_vector_type(8))) short short8;
typedef __attribute__((ext_vector_type(8))) __bf16 bf16x8;
typedef __attribute__((ext_vector_type(4))) float f32x4;

#define MFMA(a, b, c) __builtin_amdgcn_mfma_f32_16x16x32_bf16((a), (b), (c), 0, 0, 0)
#define SCALE 0.0625f

static __device__ __forceinline__ void gload16(const void* g, void* l) {
  __builtin_amdgcn_global_load_lds(
      (const __attribute__((address_space(1))) void*)g,
      (__attribute__((address_space(3))) void*)l, 16, 0, 0);
}

static __device__ __forceinline__ unsigned short f2b(float f) {
  union { __hip_bfloat16 h; unsigned short u; } cv;
  cv.h = __float2bfloat16(f);
  return cv.u;
}

// ---- fused prep: convert_x + pack_bias + transpose_w(Wq,Wk,Wv) -------------
__global__ __launch_bounds__(256) void prep_kern(
    const float* __restrict__ x, unsigned short* __restrict__ xb,
    const float* __restrict__ bq, const float* __restrict__ bk,
    const float* __restrict__ bv, float* __restrict__ bc,
    const float* __restrict__ Wq, const float* __restrict__ Wk,
    const float* __restrict__ Wv, unsigned short* __restrict__ wt) {
  __shared__ __align__(16) unsigned short tile[64][72];
  int bid = blockIdx.x, t = threadIdx.x;
  if (bid < 4096) {
    long i = ((long)bid * 256 + t) * 8;
    float4 a = *reinterpret_cast<const float4*>(x + i);
    float4 b = *reinterpret_cast<const float4*>(x + i + 4);
    short8 o;
    o[0] = (short)f2b(a.x); o[1] = (short)f2b(a.y); o[2] = (short)f2b(a.z); o[3] = (short)f2b(a.w);
    o[4] = (short)f2b(b.x); o[5] = (short)f2b(b.y); o[6] = (short)f2b(b.z); o[7] = (short)f2b(b.w);
    *reinterpret_cast<short8*>(xb + i) = o;
    return;
  }
  if (bid < 4102) {
    int i = (bid - 4096) * 256 + t;
    float v = (i < 256) ? bq[i] : (i < 512) ? bk[i - 256] : bv[i - 512];
    bc[i] = v;
    return;
  }
  const float* src; unsigned short* dst; int ldsrc, lam;
  if (bid < 4166)      { lam = bid - 4102; src = Wq; dst = wt;              ldsrc = 256;
                         lam = (lam & 3) | ((lam >> 2) << 8); }
  else if (bid < 4230) { lam = bid - 4166; src = Wk; dst = wt + 256 * 1024; ldsrc = 256;
                         lam = (lam & 3) | ((lam >> 2) << 8); }
  else                 { lam = bid - 4230; src = Wv; dst = wt + 512 * 1024; ldsrc = 1024;
                         lam = (lam & 15) | ((lam >> 4) << 8); }
  int c0 = (lam & 255) * 64, r0 = (lam >> 8) * 64;
  #pragma unroll
  for (int it = 0; it < 4; ++it) {
    int idx = it * 1024 + t * 4;
    int row = idx >> 6, col = idx & 63;
    float4 v = *reinterpret_cast<const float4*>(src + (long)(r0 + row) * ldsrc + c0 + col);
    tile[row][col + 0] = f2b(v.x); tile[row][col + 1] = f2b(v.y);
    tile[row][col + 2] = f2b(v.z); tile[row][col + 3] = f2b(v.w);
  }
  __syncthreads();
  #pragma unroll
  for (int it = 0; it < 4; ++it) {
    int idx = it * 1024 + t * 4;
    int orow = idx >> 6, ocol = idx & 63;
    ushort4 o;
    o.x = tile[ocol + 0][orow]; o.y = tile[ocol + 1][orow];
    o.z = tile[ocol + 2][orow]; o.w = tile[ocol + 3][orow];
    *reinterpret_cast<ushort4*>(dst + (long)(c0 + orow) * 1024 + r0 + ocol) = o;
  }
}

// ============================================================================
// gemm_pi (QKV + score): r11/r12-proven, unchanged.
// ============================================================================
template <int SWZ, int BN, bool BIAS, bool VSPLIT, bool EXPSUM>
__global__ __launch_bounds__(512, 2) void gemm_pi(
    const unsigned short* __restrict__ A, const unsigned short* __restrict__ B,
    const float* __restrict__ bias, void* __restrict__ Cout,
    int NT, int lda, int ldb, int ldc,
    long batchA, long batchB, long batchC,
    float* __restrict__ lpart,
    unsigned short* __restrict__ vT) {
  constexpr int WM = 128;
  constexpr int WN = BN / 4;
  constexpr int NF = BN / 64;
  constexpr int BR = BN / 64;
  constexpr int ASH = 256 * 64;
  constexpr int TSH = ASH + BN * 64;
  __shared__ __align__(128) unsigned short lds[2 * TSH];

  int bid = blockIdx.x;
  int b = 0, tm, tn;
  if constexpr (SWZ == 0) {
    int xcd = bid & 7, s = bid >> 3;
    tm = xcd * 4 + (s >> 3); tn = s & 7;
  } else {
    int xcd = bid & 7, s = bid >> 3;
    b = xcd >> 1; tm = (xcd & 1) * 4 + (s >> 3); tn = s & 7;
  }

  int t = threadIdx.x, w = t >> 6, l = t & 63;
  int wr = w >> 2, wc = w & 3;
  int g = l >> 4, c = l & 15;

  f32x4 acc[8][NF];
  #pragma unroll
  for (int m = 0; m < 8; ++m)
    #pragma unroll
    for (int n = 0; n < NF; ++n) acc[m][n] = (f32x4){0.f, 0.f, 0.f, 0.f};

  int srow = t >> 3;
  int scb = (t & 7) * 16;
  const unsigned short* aptr = A + (long)b * batchA + (long)(tm * 256) * lda;
  const unsigned short* bptr = B + (long)b * batchB + (long)(tn * BN) * ldb;
  int kb = scb ^ ((srow & 7) << 4);

  auto stageA = [&](int buf, int k0, int r) {
    int row = r * 64 + srow;
    gload16(aptr + (long)row * lda + k0 + (kb >> 1),
            lds + buf * TSH + r * 4096 + t * 8);
  };
  auto stageB = [&](int buf, int k0, int r) {
    int row = r * 64 + srow;
    gload16(bptr + (long)row * ldb + k0 + (kb >> 1),
            lds + buf * TSH + ASH + r * 4096 + t * 8);
  };
  auto ldA = [&](const char* abase, int mh, int kh, int m) {
    int row = wr * WM + mh * 64 + m * 16 + c;
    int pb = row * 128 + (kh * 32 + g * 8) * 2;
    pb ^= ((pb >> 7) & 7) << 4;
    return *reinterpret_cast<const bf16x8*>(abase + pb);
  };
  auto ldB = [&](const char* bbase, int kh, int n) {
    int row = wc * WN + n * 16 + c;
    int pb = row * 128 + (kh * 32 + g * 8) * 2;
    pb ^= ((pb >> 7) & 7) << 4;
    return *reinterpret_cast<const bf16x8*>(bbase + pb);
  };

  #pragma unroll
  for (int r = 0; r < BR; ++r) stageB(0, 0, r);
  stageA(0, 0, 0); stageA(0, 0, 2); stageA(0, 0, 1); stageA(0, 0, 3);
  asm volatile("s_waitcnt vmcnt(0)" ::: "memory");
  __builtin_amdgcn_s_barrier();

  for (int kt = 0; kt < NT; ++kt) {
    int cur = kt & 1, nb = cur ^ 1;
    const char* abase = (const char*)(lds + cur * TSH);
    const char* bbase = (const char*)(lds + cur * TSH + ASH);
    bool more = (kt + 1) < NT;
    int k1 = (kt + 1) * 64;
    bf16x8 bfr[NF];
    #pragma unroll
    for (int p = 0; p < 4; ++p) {
      const int kh = p >> 1, mh = p & 1;
      bf16x8 af[4];
      #pragma unroll
      for (int m = 0; m < 4; ++m) af[m] = ldA(abase, mh, kh, m);
      if (mh == 0) {
        #pragma unroll
        for (int n = 0; n < NF; ++n) bfr[n] = ldB(bbase, kh, n);
      }
      if (more) {
        if constexpr (BN == 256) {
          if      (p == 0) { stageB(nb, k1, 0); stageB(nb, k1, 1); }
          else if (p == 1) { stageB(nb, k1, 2); stageB(nb, k1, 3); }
          else if (p == 2) { stageA(nb, k1, 0); stageA(nb, k1, 2); }
          else             { stageA(nb, k1, 1); stageA(nb, k1, 3); }
        } else {
          if      (p == 0) { stageB(nb, k1, 0); stageB(nb, k1, 1); stageB(nb, k1, 2); }
          else if (p == 1) { stageA(nb, k1, 0); stageA(nb, k1, 2); }
          else if (p == 2) { stageA(nb, k1, 1); stageA(nb, k1, 3); }
        }
      }
      __builtin_amdgcn_s_barrier();
      asm volatile("s_waitcnt lgkmcnt(0)" ::: "memory");
      __builtin_amdgcn_sched_barrier(0);
      __builtin_amdgcn_s_setprio(1);
      #pragma unroll
      for (int m = 0; m < 4; ++m)
        #pragma unroll
        for (int n = 0; n < NF; ++n)
          acc[mh * 4 + m][n] = MFMA(af[m], bfr[n], acc[mh * 4 + m][n]);
      __builtin_amdgcn_s_setprio(0);
      if (p == 0) {
        if (kt == NT - 1) asm volatile("s_waitcnt vmcnt(0)" ::: "memory");
        else if (BN == 256) asm volatile("s_waitcnt vmcnt(2)" ::: "memory");
        else                asm volatile("s_waitcnt vmcnt(3)" ::: "memory");
      }
      if (p == 3 && more) {
        asm volatile("s_waitcnt vmcnt(2)" ::: "memory");
      }
      __builtin_amdgcn_s_barrier();
    }
  }

  int rbase = tm * 256 + wr * WM + g * 4;
  int c0 = tn * BN + wc * WN + c;

  if constexpr (EXPSUM) {
    __shared__ float lred[4][256];
    #pragma unroll
    for (int mi = 0; mi < 8; ++mi) {
      int roff = (mi / 4) * 64 + (mi % 4) * 16;
      #pragma unroll
      for (int j = 0; j < 4; ++j) {
        long ob = (long)b * batchC + (long)(rbase + roff + j) * ldc + c0;
        float rs = 0.f;
        #pragma unroll
        for (int n = 0; n < NF; ++n) {
          float pv = __expf(acc[mi][n][j] * SCALE);
          ((unsigned short*)Cout)[ob + n * 16] = f2b(pv);
          rs += pv;
        }
        rs += __shfl_xor(rs, 1); rs += __shfl_xor(rs, 2);
        rs += __shfl_xor(rs, 4); rs += __shfl_xor(rs, 8);
        if (c == 0) lred[wc][wr * WM + roff + g * 4 + j] = rs;
      }
    }
    __syncthreads();
    for (int rr = t; rr < 256; rr += 512) {
      float s = lred[0][rr] + lred[1][rr] + lred[2][rr] + lred[3][rr];
      lpart[((long)b * 2048 + tm * 256 + rr) * 8 + tn] = s;
    }
  } else {
    #pragma unroll
    for (int mi = 0; mi < 8; ++mi) {
      int roff = (mi / 4) * 64 + (mi % 4) * 16;
      int s0 = (rbase + roff) & 2047;
      #pragma unroll
      for (int n = 0; n < NF; ++n) {
        int col = c0 + n * 16;
        float bv = BIAS ? bias[col] : 0.f;
        if (VSPLIT && (col - c) >= 512) {
          int bb = tm >> 3;
          ushort4 pk;
          pk.x = f2b(acc[mi][n][0] + bv); pk.y = f2b(acc[mi][n][1] + bv);
          pk.z = f2b(acc[mi][n][2] + bv); pk.w = f2b(acc[mi][n][3] + bv);
          *reinterpret_cast<ushort4*>(vT + (long)bb * 2097152 +
                                      (long)(col - 512) * 2048 + s0) = pk;
        } else {
          long rowb = (long)b * batchC + (long)(rbase + roff) * ldc + col;
          #pragma unroll
          for (int j = 0; j < 4; ++j)
            ((unsigned short*)Cout)[rowb + (long)j * ldc] = f2b(acc[mi][n][j] + bv);
        }
      }
    }
  }
}

// ============================================================================
// gemm_pv (PV): r12-proven 16-wave TLP variant (41.8us) + linv folded into
// the prologue (r13-verified numerics). 1024 thr = 16 waves (4M x 4N), wave
// tile 32x64, BM=128/BN=256/BK=64, 3-buffer LDS (144KB), stage t+2,
// 3 loads/thread/tile -> vmcnt(3) retires tile t+1 (NT-2 -> 0).
// ============================================================================
__global__ __launch_bounds__(1024, 4) void gemm_pv(
    const unsigned short* __restrict__ A,   // attn [4][2048][2048] bf16
    const unsigned short* __restrict__ B,   // vT   [4][1024][2048] bf16
    float* __restrict__ Cout,               // out  [4][2048][1024] f32
    const float* __restrict__ lpart) {      // [4*2048][8] row partials
  constexpr int NT = 32;
  constexpr int ASH = 128 * 64;             // 16KB
  constexpr int TSH = ASH + 256 * 64;       // 48KB
  __shared__ __align__(128) unsigned short lds[3 * TSH];
  __shared__ float linv_s[128];

  int bid = blockIdx.x;                     // 256 = 8 xcd * 32
  int xcd = bid & 7, sidx = bid >> 3;
  int b = xcd >> 1;
  int tm = (xcd & 1) * 8 + (sidx >> 2), tn = sidx & 3;

  int t = threadIdx.x, w = t >> 6, l = t & 63;
  int wr = w >> 2, wc = w & 3;              // 4 x 4 wave grid
  int g = l >> 4, c = l & 15;

  // fold linv: 1/sum of the 8 per-slice partials, rows tm*128..+127
  if (t < 128) {
    const float* lp = lpart + ((long)b * 2048 + tm * 128 + t) * 8;
    float s = lp[0] + lp[1] + lp[2] + lp[3] + lp[4] + lp[5] + lp[6] + lp[7];
    linv_s[t] = 1.f / s;
  }

  f32x4 acc[2][4];
  #pragma unroll
  for (int m = 0; m < 2; ++m)
    #pragma unroll
    for (int n = 0; n < 4; ++n) acc[m][n] = (f32x4){0.f, 0.f, 0.f, 0.f};

  int srow = t >> 3;                        // 0..127
  int scb = (t & 7) * 16;
  int kb = scb ^ ((srow & 7) << 4);
  const unsigned short* aptr = A + (long)b * 4194304 + (long)(tm * 128) * 2048;
  const unsigned short* bptr = B + (long)b * 2097152 + (long)(tn * 256) * 2048;

  auto stage3 = [&](int buf, int kt2) {     // A: 1 round (128 rows), B: 2
    int k0 = kt2 * 64;
    gload16(aptr + (long)srow * 2048 + k0 + (kb >> 1),
            lds + buf * TSH + t * 8);
    #pragma unroll
    for (int r = 0; r < 2; ++r) {
      int row = r * 128 + srow;
      gload16(bptr + (long)row * 2048 + k0 + (kb >> 1),
              lds + buf * TSH + ASH + r * 8192 + t * 8);
    }
  };

  stage3(0, 0); stage3(1, 1);
  asm volatile("s_waitcnt vmcnt(3)" ::: "memory");
  __builtin_amdgcn_s_barrier();

  for (int kt = 0; kt < NT; ++kt) {
    const char* abase = (const char*)(lds + (kt % 3) * TSH);
    const char* bbase = abase + ASH * 2;

    bf16x8 af[2][2], bf[2][4];
    #pragma unroll
    for (int sk = 0; sk < 2; ++sk) {
      #pragma unroll
      for (int m = 0; m < 2; ++m) {
        int p = (wr * 32 + m * 16 + c) * 128 + (sk * 32 + g * 8) * 2;
        p ^= ((p >> 7) & 7) << 4;
        af[sk][m] = *reinterpret_cast<const bf16x8*>(abase + p);
      }
      #pragma unroll
      for (int n = 0; n < 4; ++n) {
        int p = (wc * 64 + n * 16 + c) * 128 + (sk * 32 + g * 8) * 2;
        p ^= ((p >> 7) & 7) << 4;
        bf[sk][n] = *reinterpret_cast<const bf16x8*>(bbase + p);
      }
    }

    if (kt + 2 < NT) stage3((kt + 2) % 3, kt + 2);

    __builtin_amdgcn_s_setprio(1);
    #pragma unroll
    for (int sk = 0; sk < 2; ++sk)
      #pragma unroll
      for (int m = 0; m < 2; ++m)
        #pragma unroll
        for (int n = 0; n < 4; ++n)
          acc[m][n] = MFMA(af[sk][m], bf[sk][n], acc[m][n]);
    __builtin_amdgcn_s_setprio(0);

    if (kt < NT - 1) {
      if (kt == NT - 2) asm volatile("s_waitcnt vmcnt(0)" ::: "memory");
      else              asm volatile("s_waitcnt vmcnt(3)" ::: "memory");
      __builtin_amdgcn_s_barrier();
    }
  }

  // epilogue: C/D layout col = lane&15, row = (lane>>4)*4 + j
  int rloc = wr * 32 + g * 4;
  int c0 = tn * 256 + wc * 64 + c;
  #pragma unroll
  for (int mi = 0; mi < 2; ++mi) {
    float lv[4];
    #pragma unroll
    for (int j = 0; j < 4; ++j)
      lv[j] = linv_s[rloc + mi * 16 + j];
    #pragma unroll
    for (int n = 0; n < 4; ++n) {
      long rowb = (long)b * 2097152 + (long)(tm * 128 + rloc + mi * 16) * 1024
                + c0 + n * 16;
      #pragma unroll
      for (int j = 0; j < 4; ++j)
        Cout[rowb + (long)j * 1024] = acc[mi][n][j] * lv[j];
    }
  }
}

extern "C" void kernel_launch(void* const* d_in, const int* in_sizes, int n_in,
                              void* d_out, int out_size, void* d_ws, size_t ws_size,
                              hipStream_t stream) {
  (void)in_sizes; (void)n_in; (void)out_size; (void)ws_size;
  const float* x  = (const float*)d_in[0];
  const float* Wq = (const float*)d_in[1];
  const float* bq = (const float*)d_in[2];
  const float* Wk = (const float*)d_in[3];
  const float* bk = (const float*)d_in[4];
  const float* Wv = (const float*)d_in[5];
  const float* bv = (const float*)d_in[6];
  float* out = (float*)d_out;
  char* ws = (char*)d_ws;

  unsigned short* xb   = (unsigned short*)(ws + 0);          // 16,777,216
  float*          lpart= (float*)         (ws + 0);          //    262,144 (overlay)
  unsigned short* wt   = (unsigned short*)(ws + 16777216);   //  3,145,728
  float*          bc   = (float*)         (ws + 19922944);   //      6,144
  unsigned short* qkv  = (unsigned short*)(ws + 19929088);   // 25,165,824
  unsigned short* vT   = (unsigned short*)(ws + 45094912);   // 16,777,216
  unsigned short* attn = (unsigned short*)(ws + 61872128);   // 33,554,432

  // fused prep (convert_x + pack_bias + Wq/Wk/Wv transpose)
  prep_kern<<<4486, 256, 0, stream>>>(x, xb, bq, bk, bv, bc, Wq, Wk, Wv, wt);

  // qkv = xb @ wt^T + bias; V columns stream directly to vT (BN=192, 256 blk)
  gemm_pi<0, 192, true, true, false><<<dim3(256), 512, 0, stream>>>(
      xb, wt, bc, qkv, 16, 1024, 1024, 1536, 0, 0, 0, nullptr, vT);

  // attn = exp(q.k/16) (unnormalized) + row partial sums
  gemm_pi<1, 256, false, false, true><<<dim3(256), 512, 0, stream>>>(
      qkv, qkv + 256, nullptr, attn, 4, 1536, 1536, 2048,
      (long)2048 * 1536, (long)2048 * 1536, (long)2048 * 2048, lpart, nullptr);

  // out = (attn @ vT^T) * linv  (16-wave TLP variant, linv folded in)
  gemm_pv<<<dim3(256), 1024, 0, stream>>>(attn, vT, out, lpart);
}